// Round 19
// baseline (616.397 us; speedup 1.0000x reference)
//
#include <hip/hip_runtime.h>

#define N_ATOMS 200000
#define N_EDGES 800000
#define FDIM    133
#define HID     256
#define NMOLS   8000
#define CAP     32   // Poisson(4) in-degree; P(deg>=32) ~ 1e-20

typedef unsigned short bf16_t;
typedef __attribute__((ext_vector_type(4))) float f32x4;
typedef __attribute__((ext_vector_type(8))) short bf16x8;

__device__ inline float bf2f(bf16_t u) {
    union { unsigned int i; float f; } v; v.i = ((unsigned int)u) << 16; return v.f;
}
__device__ inline bf16_t f2bf(float f) {
    union { float f; unsigned int i; } v; v.f = f;
    return (bf16_t)((v.i + 0x7fffu + ((v.i >> 16) & 1u)) >> 16);   // RNE
}
__device__ inline float4 ld4(const bf16_t* p) {
    ushort4 u = *(const ushort4*)p;
    return make_float4(bf2f(u.x), bf2f(u.y), bf2f(u.z), bf2f(u.w));
}

// async global->LDS, 16B/lane; lds dest is wave-uniform base (+lane*16 implicit)
__device__ inline void gload_lds16(const void* g, void* l) {
    __builtin_amdgcn_global_load_lds((const __attribute__((address_space(1))) unsigned int*)g,
                                     (__attribute__((address_space(3))) unsigned int*)l,
                                     16, 0, 0);
}

// ---------------- adjacency build (edge_index arrives as int32) ----------------
__global__ __launch_bounds__(256) void build_adj(const int* __restrict__ ei,
                                                 int* __restrict__ cnt,
                                                 int* __restrict__ lst) {
    int e = blockIdx.x * 256 + threadIdx.x;
    if (e >= N_EDGES) return;
    int s = ei[e];
    int t = ei[N_EDGES + e];
    int p = atomicAdd(&cnt[t], 1);
    if (p < CAP) lst[t * CAP + p] = s;
}

// ---------------- weight transpose+convert: Wt[n][k] = bf16(W[k][n]), zero-pad k>=K ----------------
__global__ __launch_bounds__(256) void transpose_w(const float* __restrict__ W,
                                                   bf16_t* __restrict__ Wt,
                                                   int K, int Kpad) {
    int idx = blockIdx.x * 256 + threadIdx.x;
    if (idx >= HID * Kpad) return;
    int n = idx / Kpad, k = idx - n * Kpad;
    Wt[idx] = (k < K) ? f2bf(W[k * HID + n]) : (bf16_t)0;
}

// ---------------- B-panel-resident barrier-free MFMA GEMM + fused dot partials ----------------
// H[M x 256] = A[M x K] @ W (Wt[256][KP] = W^T bf16, K zero-padded).
// r18 post-mortem: gemm pinned at 103-115us across SIX schedule variants while
// occupancy went 37->57% -- the per-K-step barrier convoy is the cost (m233).
// This kernel removes ALL barriers from the K-loop: the block's entire B panel
// (128 cols x K = 64KB max) is staged to LDS ONCE; each wave then streams its
// A fragments DIRECT global->reg (16B aligned) and ds_reads B -- waves fully
// decoupled, compiler pipelines A-loads across the unrolled K-loop.
// Bs rows are 512B (KP=256) -> 16-way bank conflict; fixed by T2 XOR swizzle
// (kb ^= (col&7)<<4) applied on the PRE-SWIZZLED global source (gload_lds
// writes linearly, m104/m173) and on the read side. KP=160 (layer 0) is only
// 2-way aliased -> linear.
// Block: 128 rows x 128 cols, 8 waves (4 row-grp x 2 col-grp), 2x4 frags
// (32 AGPR). Grid (1563, 2). Epilogue: H store + dots -> red LDS -> 2-slot
// ssp/stp (unique writer per blockIdx.y); combine sums slots -- same
// association tree as r15 -> ss/st bit-identical.
template <bool A_FP32, int KSTEPS, int LDA, int KP>
__global__ __launch_bounds__(512, 4) void gemm_mfma(const void* __restrict__ Av,
                                                    const bf16_t* __restrict__ Wt,
                                                    bf16_t* __restrict__ H,
                                                    const float* __restrict__ avec,
                                                    float* __restrict__ ssp,
                                                    float* __restrict__ stp) {
    constexpr bool SWZ = (KP == 256);
    __shared__ bf16_t Bs[128 * KP];     // 64KB (KP=256) / 40KB (KP=160), [col][k]
    __shared__ float  red[2][128][2];   // 2KB: [ss/st][row-in-block][wc]
    const int tid  = threadIdx.x;
    const int lane = tid & 63;
    const int w    = tid >> 6;       // wave 0..7
    const int wr   = w >> 1;         // row-group 0..3 (32 rows each)
    const int wc   = w & 1;          // col-group 0..1 (64 cols each)
    const int fr   = lane & 15;
    const int kg   = lane >> 4;      // k-group 0..3
    const int row0 = blockIdx.x * 128;
    const int n0   = blockIdx.y * 128;

    // ---- one-time B-panel stage: 128*KP*2 bytes = KSTEPS * 8192 ----
    {
        const char* panel = (const char*)Wt + (long long)n0 * (KP * 2);
        #pragma unroll
        for (int it = 0; it < KSTEPS; ++it) {
            int u = it * 8192 + tid * 16;          // flat LDS byte offset (linear dest)
            int src;
            if constexpr (SWZ) {
                int col = u >> 9;                  // 512 B per col-row
                int kb  = u & 511;
                src = (col << 9) + (kb ^ ((col & 7) << 4));   // pre-swizzled source
            } else {
                src = u;                           // linear (KP=160: 2-way alias, free)
            }
            gload_lds16(panel + src, (char*)Bs + it * 8192 + w * 1024);
        }
    }
    __syncthreads();   // drains vmcnt+lgkm: full B panel resident. ONLY loop barrier.

    // ---- barrier-free K-loop: A direct global->reg, B from LDS ----
    f32x4 acc[2][4] = {};
    int ar[2];
    #pragma unroll
    for (int i = 0; i < 2; ++i) {
        int r = row0 + wr * 32 + i * 16 + fr;
        ar[i] = (r < N_ATOMS) ? r : (N_ATOMS - 1);
    }

    #pragma unroll
    for (int ks = 0; ks < KSTEPS; ++ks) {
        const int kbase = ks * 32 + kg * 8;
        bf16x8 af[2], bf[4];

        if constexpr (A_FP32) {
            const float* A = (const float*)Av;
            #pragma unroll
            for (int i = 0; i < 2; ++i) {
                const float* src = A + (long long)ar[i] * LDA + kbase;
                short v[8];
                #pragma unroll
                for (int j = 0; j < 8; ++j)
                    v[j] = (kbase + j < LDA) ? (short)f2bf(src[j]) : (short)0;
                af[i] = *(bf16x8*)v;
            }
        } else {
            const bf16_t* A = (const bf16_t*)Av;
            #pragma unroll
            for (int i = 0; i < 2; ++i)
                af[i] = *(const bf16x8*)(A + (long long)ar[i] * LDA + kbase);
        }

        #pragma unroll
        for (int jn = 0; jn < 4; ++jn) {
            int col = wc * 64 + jn * 16 + fr;
            int kb  = kbase * 2;                   // byte offset in col-row
            int off;
            if constexpr (SWZ) off = (col << 9) + (kb ^ ((col & 7) << 4));
            else               off = col * (KP * 2) + kb;
            bf[jn] = *(const bf16x8*)((const char*)Bs + off);
        }

        #pragma unroll
        for (int i = 0; i < 2; ++i)
            #pragma unroll
            for (int jn = 0; jn < 4; ++jn)
                acc[i][jn] = __builtin_amdgcn_mfma_f32_16x16x32_bf16(af[i], bf[jn], acc[i][jn], 0, 0, 0);
    }

    // ---- epilogue: H store + dot partials -> LDS -> per-block ssp/stp slot ----
    float as_v[4], at_v[4];
    #pragma unroll
    for (int jn = 0; jn < 4; ++jn) {
        int c = n0 + wc * 64 + jn * 16 + fr;
        as_v[jn] = avec[c];
        at_v[jn] = avec[HID + c];
    }
    #pragma unroll
    for (int i = 0; i < 2; ++i) {
        #pragma unroll
        for (int rr = 0; rr < 4; ++rr) {
            int row_l = wr * 32 + i * 16 + kg * 4 + rr;   // 0..127
            int r = row0 + row_l;
            float ps = 0.f, pt = 0.f;
            #pragma unroll
            for (int jn = 0; jn < 4; ++jn) {
                float h = acc[i][jn][rr];
                ps += h * as_v[jn];
                pt += h * at_v[jn];
                if (r < N_ATOMS)
                    H[(long long)r * HID + (n0 + wc * 64 + jn * 16 + fr)] = f2bf(h);
            }
            #pragma unroll
            for (int o = 1; o < 16; o <<= 1) {   // reduce across the 16 col-lanes
                ps += __shfl_xor(ps, o);
                pt += __shfl_xor(pt, o);
            }
            if (fr == 0) {
                red[0][row_l][wc] = ps;          // unique writer per (row_l, wc)
                red[1][row_l][wc] = pt;
            }
        }
    }
    __syncthreads();
    if (tid < 128) {
        int r = row0 + tid;
        if (r < N_ATOMS) {
            long long slot = (long long)blockIdx.y * N_ATOMS + r;
            ssp[slot] = red[0][tid][0] + red[0][tid][1];   // cols n0..n0+127 partial
            stp[slot] = red[1][tid][0] + red[1][tid][1];
        }
    }
}

// ---------------- combine the 2 column-half dot partials ----------------
// ss = (c0..127) + (c128..255): same association tree as r15's reduce.
__global__ __launch_bounds__(256) void combine_dots(const float* __restrict__ ssp,
                                                    const float* __restrict__ stp,
                                                    float* __restrict__ ss,
                                                    float* __restrict__ st) {
    int i = blockIdx.x * 256 + threadIdx.x;
    if (i >= N_ATOMS) return;
    ss[i] = ssp[i] + ssp[N_ATOMS + i];
    st[i] = stp[i] + stp[N_ATOMS + i];
}

// ---------------- half-wave fused softmax-aggregate + residual + ELU (r14, unchanged) ----------------
__global__ __launch_bounds__(256) void aggregate(const bf16_t* __restrict__ H,
                                                 const float* __restrict__ ss,
                                                 const float* __restrict__ st,
                                                 const int* __restrict__ cnt,
                                                 const int* __restrict__ lst,
                                                 bf16_t* __restrict__ X,
                                                 int residual) {
    const int tid  = threadIdx.x;
    const int lane = tid & 63;
    const int wv   = (blockIdx.x * 256 + tid) >> 6;   // 0..99999
    const int half = lane >> 5;
    const int sub  = lane & 31;
    const int t    = 2 * wv + half;                   // < 200000 exactly

    int n = cnt[t]; if (n > CAP) n = CAP;

    const float stt = st[t];
    const unsigned rowoff = (unsigned)t * (HID * 2);
    const unsigned loff   = (unsigned)sub * 16;
    const unsigned lbase  = (unsigned)t * (CAP * 4);

    float acc[8] = {0.f, 0.f, 0.f, 0.f, 0.f, 0.f, 0.f, 0.f};
    float denom = 0.f;

    for (int i0 = 0; i0 < n; i0 += 4) {
        int4 s4 = *(const int4*)((const char*)lst + (lbase + (unsigned)i0 * 4));
        int s0 = s4.x;
        int s1 = (i0 + 1 < n) ? s4.y : s4.x;
        int s2 = (i0 + 2 < n) ? s4.z : s4.x;
        int s3 = (i0 + 3 < n) ? s4.w : s4.x;

        float v0 = ss[s0], v1 = ss[s1], v2 = ss[s2], v3 = ss[s3];

        bf16x8 r0 = *(const bf16x8*)((const char*)H + ((unsigned)s0 * 512u + loff));
        bf16x8 r1 = *(const bf16x8*)((const char*)H + ((unsigned)s1 * 512u + loff));
        bf16x8 r2 = *(const bf16x8*)((const char*)H + ((unsigned)s2 * 512u + loff));
        bf16x8 r3 = *(const bf16x8*)((const char*)H + ((unsigned)s3 * 512u + loff));

        float e0 = v0 + stt; e0 = e0 > 0.f ? e0 : 0.2f * e0;
        float e1 = v1 + stt; e1 = e1 > 0.f ? e1 : 0.2f * e1;
        float e2 = v2 + stt; e2 = e2 > 0.f ? e2 : 0.2f * e2;
        float e3 = v3 + stt; e3 = e3 > 0.f ? e3 : 0.2f * e3;

        float w0 = __expf(e0);
        float w1 = (i0 + 1 < n) ? __expf(e1) : 0.f;
        float w2 = (i0 + 2 < n) ? __expf(e2) : 0.f;
        float w3 = (i0 + 3 < n) ? __expf(e3) : 0.f;

        denom += (w0 + w1) + (w2 + w3);
        #pragma unroll
        for (int e = 0; e < 8; ++e) {
            acc[e] += w0 * bf2f((bf16_t)r0[e]) + w1 * bf2f((bf16_t)r1[e])
                    + w2 * bf2f((bf16_t)r2[e]) + w3 * bf2f((bf16_t)r3[e]);
        }
    }

    const float inv = 1.f / (denom + 1e-8f);
    float r[8];
    #pragma unroll
    for (int e = 0; e < 8; ++e) r[e] = acc[e] * inv;

    if (residual) {
        bf16x8 xv = *(const bf16x8*)((const char*)X + (rowoff + loff));
        #pragma unroll
        for (int e = 0; e < 8; ++e) r[e] += bf2f((bf16_t)xv[e]);
    }

    bf16x8 o;
    #pragma unroll
    for (int e = 0; e < 8; ++e) {
        float x = r[e];
        x = x > 0.f ? x : (__expf(x) - 1.f);   // elu(alpha=1)
        o[e] = (short)f2bf(x);
    }
    *(bf16x8*)((char*)X + (rowoff + loff)) = o;
}

// ---------------- molecule mean pool (mol_ids int32, sorted) ----------------
__device__ inline int lower_bound_i(const int* a, int n, int v) {
    int lo = 0, hi = n;
    while (lo < hi) { int mid = (lo + hi) >> 1; if (a[mid] < v) lo = mid + 1; else hi = mid; }
    return lo;
}

__global__ __launch_bounds__(64) void pool_kernel(const bf16_t* __restrict__ X,
                                                  const int* __restrict__ mol,
                                                  float* __restrict__ out) {
    int m = blockIdx.x;
    int lane = threadIdx.x;
    int lo = lower_bound_i(mol, N_ATOMS, m);
    int hi = lower_bound_i(mol, N_ATOMS, m + 1);
    float ax = 0.f, ay = 0.f, az = 0.f, aw = 0.f;
    for (int i = lo; i < hi; ++i) {
        float4 v = ld4(&X[(long long)i * HID + lane * 4]);
        ax += v.x; ay += v.y; az += v.z; aw += v.w;
    }
    float c = (float)(hi - lo);
    float4 r = make_float4(0.f, 0.f, 0.f, 0.f);
    if (c > 0.f) {
        float inv = 1.f / c;
        r = make_float4(ax * inv, ay * inv, az * inv, aw * inv);
    }
    *(float4*)&out[(long long)m * HID + lane * 4] = r;
}

extern "C" void kernel_launch(void* const* d_in, const int* in_sizes, int n_in,
                              void* d_out, int out_size, void* d_ws, size_t ws_size,
                              hipStream_t stream) {
    const float* f_atoms = (const float*)d_in[0];
    const int*   ei      = (const int*)d_in[1];
    const int*   mol     = (const int*)d_in[2];
    const float* W0      = (const float*)d_in[3];
    const float* a0      = (const float*)d_in[4];
    const float* W1      = (const float*)d_in[5];
    const float* a1      = (const float*)d_in[6];
    const float* W2      = (const float*)d_in[7];
    const float* a2      = (const float*)d_in[8];
    float* out = (float*)d_out;

    char* ws = (char*)d_ws;
    size_t off = 0;
    bf16_t* X  = (bf16_t*)(ws + off); off += (size_t)N_ATOMS * HID * 2;   // 102.4 MB
    bf16_t* Hb = (bf16_t*)(ws + off); off += (size_t)N_ATOMS * HID * 2;   // 102.4 MB
    float* ss  = (float*)(ws + off);  off += (size_t)N_ATOMS * 4;
    float* st  = (float*)(ws + off);  off += (size_t)N_ATOMS * 4;
    int* cnt   = (int*)(ws + off);    off += (size_t)N_ATOMS * 4;
    int* lst   = (int*)(ws + off);    off += (size_t)N_ATOMS * CAP * 4;   // 25.6 MB
    if (ws_size < off) return;

    // d_out scratch: Wt 131KB + 2-slot ssp/stp (1.6 MB each); pool overwrites all.
    char* ob = (char*)d_out;
    bf16_t* Wt  = (bf16_t*)ob;                       // 131072 B
    float*  ssp = (float*)(ob + 131072);             // 2 x N_ATOMS f32
    float*  stp = (float*)(ob + 131072 + 1600000);   // 2 x N_ATOMS f32

    hipMemsetAsync(cnt, 0, (size_t)N_ATOMS * 4, stream);
    build_adj<<<(N_EDGES + 255) / 256, 256, 0, stream>>>(ei, cnt, lst);

    const dim3 gemm_grid((N_ATOMS + 127) / 128, 2);   // 1563 x 2
    const int  agg_blocks = N_ATOMS / 8;              // 25000
    const int  cmb_blocks = (N_ATOMS + 255) / 256;

    // ---- layer 0: A = f_atoms fp32, K=133 padded to 160 ----
    transpose_w<<<(HID * 160 + 255) / 256, 256, 0, stream>>>(W0, Wt, FDIM, 160);
    gemm_mfma<true, 5, FDIM, 160><<<gemm_grid, 512, 0, stream>>>(f_atoms, Wt, Hb, a0, ssp, stp);
    combine_dots<<<cmb_blocks, 256, 0, stream>>>(ssp, stp, ss, st);
    aggregate<<<agg_blocks, 256, 0, stream>>>(Hb, ss, st, cnt, lst, X, 0);

    // ---- layer 1 ----
    transpose_w<<<(HID * HID + 255) / 256, 256, 0, stream>>>(W1, Wt, HID, HID);
    gemm_mfma<false, 8, HID, HID><<<gemm_grid, 512, 0, stream>>>(X, Wt, Hb, a1, ssp, stp);
    combine_dots<<<cmb_blocks, 256, 0, stream>>>(ssp, stp, ss, st);
    aggregate<<<agg_blocks, 256, 0, stream>>>(Hb, ss, st, cnt, lst, X, 1);

    // ---- layer 2 ----
    transpose_w<<<(HID * HID + 255) / 256, 256, 0, stream>>>(W2, Wt, HID, HID);
    gemm_mfma<false, 8, HID, HID><<<gemm_grid, 512, 0, stream>>>(X, Wt, Hb, a2, ssp, stp);
    combine_dots<<<cmb_blocks, 256, 0, stream>>>(ssp, stp, ss, st);
    aggregate<<<agg_blocks, 256, 0, stream>>>(Hb, ss, st, cnt, lst, X, 1);

    pool_kernel<<<NMOLS, 64, 0, stream>>>(X, mol, out);
}

// Round 20
// 544.508 us; speedup vs baseline: 1.1320x; 1.1320x over previous
//
#include <hip/hip_runtime.h>

#define N_ATOMS 200000
#define N_EDGES 800000
#define FDIM    133
#define HID     256
#define NMOLS   8000
#define CAP     32   // Poisson(4) in-degree; P(deg>=32) ~ 1e-20

typedef unsigned short bf16_t;
typedef __attribute__((ext_vector_type(4))) float f32x4;
typedef __attribute__((ext_vector_type(8))) short bf16x8;

__device__ inline float bf2f(bf16_t u) {
    union { unsigned int i; float f; } v; v.i = ((unsigned int)u) << 16; return v.f;
}
__device__ inline bf16_t f2bf(float f) {
    union { float f; unsigned int i; } v; v.f = f;
    return (bf16_t)((v.i + 0x7fffu + ((v.i >> 16) & 1u)) >> 16);   // RNE
}
__device__ inline float4 ld4(const bf16_t* p) {
    ushort4 u = *(const ushort4*)p;
    return make_float4(bf2f(u.x), bf2f(u.y), bf2f(u.z), bf2f(u.w));
}

// async global->LDS, 16B/lane; lds dest is wave-uniform base (+lane*16 implicit)
__device__ inline void gload_lds16(const void* g, void* l) {
    __builtin_amdgcn_global_load_lds((const __attribute__((address_space(1))) unsigned int*)g,
                                     (__attribute__((address_space(3))) unsigned int*)l,
                                     16, 0, 0);
}

// ---------------- adjacency build (edge_index arrives as int32) ----------------
__global__ __launch_bounds__(256) void build_adj(const int* __restrict__ ei,
                                                 int* __restrict__ cnt,
                                                 int* __restrict__ lst) {
    int e = blockIdx.x * 256 + threadIdx.x;
    if (e >= N_EDGES) return;
    int s = ei[e];
    int t = ei[N_EDGES + e];
    int p = atomicAdd(&cnt[t], 1);
    if (p < CAP) lst[t * CAP + p] = s;
}

// ---------------- fused weight transpose+convert for ALL THREE layers ----------------
// Wt0[n][k] (Kpad=160, K=133 zero-padded), Wt1/Wt2[n][k] (Kpad=256).
// One dispatch replaces three -> two fewer launch gaps on the serial stream.
__global__ __launch_bounds__(256) void transpose_all(const float* __restrict__ W0,
                                                     const float* __restrict__ W1,
                                                     const float* __restrict__ W2,
                                                     bf16_t* __restrict__ Wt0,
                                                     bf16_t* __restrict__ Wt1,
                                                     bf16_t* __restrict__ Wt2) {
    int idx = blockIdx.x * 256 + threadIdx.x;
    if (idx < HID * 160) {
        int n = idx / 160, k = idx - n * 160;
        Wt0[idx] = (k < FDIM) ? f2bf(W0[k * HID + n]) : (bf16_t)0;
        return;
    }
    idx -= HID * 160;
    if (idx < HID * HID) {
        int n = idx >> 8, k = idx & 255;
        Wt1[idx] = f2bf(W1[k * HID + n]);
        return;
    }
    idx -= HID * HID;
    if (idx < HID * HID) {
        int n = idx >> 8, k = idx & 255;
        Wt2[idx] = f2bf(W2[k * HID + n]);
    }
}

// ---------------- 8-wave full-N MFMA GEMM + fused dots (r14 measured-best) ----------------
// H[M x 256] = A[M x K] @ W (Wt[256][KP] = W^T bf16, K zero-padded).
// Block = 128 rows x 256 cols, 8 waves (2 row-groups x 4 col-groups), dbuf LDS.
// bf16 path: counted-vmcnt pipeline (3 gloads/thread/tile -> vmcnt(3); loads
// stay in flight across the barrier). fp32-A path (layer 0): reg-staged A,
// classic __syncthreads dbuf. Epilogue: bf16 H store + per-wave 64-col dot
// partials -> LDS -> ss/st directly.
template <bool A_FP32, int KSTEPS, int LDA, int KP>
__global__ __launch_bounds__(512, 4) void gemm_mfma(const void* __restrict__ Av,
                                                    const bf16_t* __restrict__ Wt,
                                                    bf16_t* __restrict__ H,
                                                    const float* __restrict__ avec,
                                                    float* __restrict__ ss_o,
                                                    float* __restrict__ st_o) {
    __shared__ bf16_t As[2][128][32];   // 2 x 8 KB
    __shared__ bf16_t Bs[2][256][32];   // 2 x 16 KB
    __shared__ float  red[2][128][4];   // 4 KB
    const int tid  = threadIdx.x;
    const int lane = tid & 63;
    const int w    = tid >> 6;
    const int wr   = w >> 2;
    const int wc   = w & 3;
    const int fr   = lane & 15;
    const int kg   = lane >> 4;
    const int row0 = blockIdx.x * 128;

    const int sra  = tid >> 2;
    const int ska  = (tid & 3) * 8;
    int sgrow = row0 + sra; if (sgrow >= N_ATOMS) sgrow = N_ATOMS - 1;

    float sreg[8];

#define ISSUE(ks_, buf_) do {                                                          \
    const int k0_ = (ks_) * 32;                                                        \
    if constexpr (A_FP32) {                                                            \
        _Pragma("unroll")                                                              \
        for (int j = 0; j < 8; ++j) {                                                  \
            int gk = k0_ + ska + j;                                                    \
            sreg[j] = (gk < LDA) ? ((const float*)Av)[(long long)sgrow * LDA + gk] : 0.f; \
        }                                                                              \
    } else {                                                                           \
        gload_lds16((const bf16_t*)Av + (long long)sgrow * LDA + k0_ + ska,            \
                    (char*)&As[buf_][0][0] + w * 1024);                                \
    }                                                                                  \
    gload_lds16(Wt + (long long)(tid >> 2) * KP + k0_ + ska,                           \
                (char*)&Bs[buf_][0][0] + w * 1024);                                    \
    gload_lds16(Wt + (long long)(128 + (tid >> 2)) * KP + k0_ + ska,                   \
                (char*)&Bs[buf_][0][0] + 8192 + w * 1024);                             \
} while (0)

#define COMMIT(buf_) do {                                                              \
    if constexpr (A_FP32) {                                                            \
        short v_[8];                                                                   \
        _Pragma("unroll")                                                              \
        for (int j = 0; j < 8; ++j) v_[j] = (short)f2bf(sreg[j]);                      \
        *(bf16x8*)&As[buf_][sra][ska] = *(bf16x8*)&v_[0];                              \
    }                                                                                  \
} while (0)

#define READ_FRAGS(buf_, af_, bf_) do {                                                \
    const int koff_ = kg * 8;                                                          \
    _Pragma("unroll")                                                                  \
    for (int i = 0; i < 4; ++i)                                                        \
        af_[i] = *(const bf16x8*)&As[buf_][wr * 64 + i * 16 + fr][koff_];              \
    _Pragma("unroll")                                                                  \
    for (int jn = 0; jn < 4; ++jn)                                                     \
        bf_[jn] = *(const bf16x8*)&Bs[buf_][wc * 64 + jn * 16 + fr][koff_];            \
} while (0)

#define DO_MFMA(af_, bf_) do {                                                         \
    _Pragma("unroll")                                                                  \
    for (int i = 0; i < 4; ++i)                                                        \
        _Pragma("unroll")                                                              \
        for (int jn = 0; jn < 4; ++jn)                                                 \
            acc[i][jn] = __builtin_amdgcn_mfma_f32_16x16x32_bf16(af_[i], bf_[jn], acc[i][jn], 0, 0, 0); \
} while (0)

    f32x4 acc[4][4] = {};

    if constexpr (A_FP32) {
        // ---- layer-0 loop: reg-staged A, classic __syncthreads dbuf ----
        ISSUE(0, 0);
        COMMIT(0);
        __syncthreads();
        int buf = 0;
        for (int ks = 0; ks < KSTEPS; ++ks) {
            if (ks + 1 < KSTEPS) ISSUE(ks + 1, buf ^ 1);
            bf16x8 af[4], bfr[4];
            READ_FRAGS(buf, af, bfr);
            DO_MFMA(af, bfr);
            if (ks + 1 < KSTEPS) COMMIT(buf ^ 1);
            __syncthreads();
            buf ^= 1;
        }
    } else {
        // ---- bf16 loop: counted-vmcnt pipeline (3 gloads/thread/tile) ----
        ISSUE(0, 0);
        int buf = 0;
        for (int ks = 0; ks < KSTEPS; ++ks) {
            if (ks + 1 < KSTEPS) {
                ISSUE(ks + 1, buf ^ 1);                           // 6 outstanding
                asm volatile("s_waitcnt vmcnt(3)" ::: "memory");  // tile ks resident, ks+1 flying
            } else {
                asm volatile("s_waitcnt vmcnt(0)" ::: "memory");  // final tile
            }
            __builtin_amdgcn_s_barrier();                     // all waves' tile-ks loads done

            bf16x8 af[4], bfr[4];
            READ_FRAGS(buf, af, bfr);
            asm volatile("s_waitcnt lgkmcnt(0)" ::: "memory"); // my reads complete
            __builtin_amdgcn_sched_barrier(0);                 // don't sink reads past barrier
            __builtin_amdgcn_s_barrier();                      // buf safe to overwrite next iter

            DO_MFMA(af, bfr);                                  // register-only, overlaps next ISSUE
            buf ^= 1;
        }
    }
#undef ISSUE
#undef COMMIT
#undef READ_FRAGS
#undef DO_MFMA

    // ---- epilogue: H store + dot partials -> LDS -> final ss/st ----
    float as_v[4], at_v[4];
    #pragma unroll
    for (int jn = 0; jn < 4; ++jn) {
        int c = wc * 64 + jn * 16 + fr;
        as_v[jn] = avec[c];
        at_v[jn] = avec[HID + c];
    }
    #pragma unroll
    for (int i = 0; i < 4; ++i) {
        #pragma unroll
        for (int rr = 0; rr < 4; ++rr) {
            int row_l = wr * 64 + i * 16 + kg * 4 + rr;
            int r = row0 + row_l;
            float ps = 0.f, pt = 0.f;
            #pragma unroll
            for (int jn = 0; jn < 4; ++jn) {
                float h = acc[i][jn][rr];
                ps += h * as_v[jn];
                pt += h * at_v[jn];
                if (r < N_ATOMS)
                    H[(long long)r * HID + (wc * 64 + jn * 16 + fr)] = f2bf(h);
            }
            #pragma unroll
            for (int o = 1; o < 16; o <<= 1) {
                ps += __shfl_xor(ps, o);
                pt += __shfl_xor(pt, o);
            }
            if (fr == 0) {
                red[0][row_l][wc] = ps;
                red[1][row_l][wc] = pt;
            }
        }
    }
    __syncthreads();
    if (tid < 128) {
        int r = row0 + tid;
        if (r < N_ATOMS) {
            ss_o[r] = (red[0][tid][0] + red[0][tid][1]) + (red[0][tid][2] + red[0][tid][3]);
            st_o[r] = (red[1][tid][0] + red[1][tid][1]) + (red[1][tid][2] + red[1][tid][3]);
        }
    }
}

// ---------------- half-wave fused softmax-aggregate + residual + ELU (r14, unchanged) ----------------
__global__ __launch_bounds__(256) void aggregate(const bf16_t* __restrict__ H,
                                                 const float* __restrict__ ss,
                                                 const float* __restrict__ st,
                                                 const int* __restrict__ cnt,
                                                 const int* __restrict__ lst,
                                                 bf16_t* __restrict__ X,
                                                 int residual) {
    const int tid  = threadIdx.x;
    const int lane = tid & 63;
    const int wv   = (blockIdx.x * 256 + tid) >> 6;   // 0..99999
    const int half = lane >> 5;
    const int sub  = lane & 31;
    const int t    = 2 * wv + half;                   // < 200000 exactly

    int n = cnt[t]; if (n > CAP) n = CAP;

    const float stt = st[t];
    const unsigned rowoff = (unsigned)t * (HID * 2);
    const unsigned loff   = (unsigned)sub * 16;
    const unsigned lbase  = (unsigned)t * (CAP * 4);

    float acc[8] = {0.f, 0.f, 0.f, 0.f, 0.f, 0.f, 0.f, 0.f};
    float denom = 0.f;

    for (int i0 = 0; i0 < n; i0 += 4) {
        int4 s4 = *(const int4*)((const char*)lst + (lbase + (unsigned)i0 * 4));
        int s0 = s4.x;
        int s1 = (i0 + 1 < n) ? s4.y : s4.x;
        int s2 = (i0 + 2 < n) ? s4.z : s4.x;
        int s3 = (i0 + 3 < n) ? s4.w : s4.x;

        float v0 = ss[s0], v1 = ss[s1], v2 = ss[s2], v3 = ss[s3];

        bf16x8 r0 = *(const bf16x8*)((const char*)H + ((unsigned)s0 * 512u + loff));
        bf16x8 r1 = *(const bf16x8*)((const char*)H + ((unsigned)s1 * 512u + loff));
        bf16x8 r2 = *(const bf16x8*)((const char*)H + ((unsigned)s2 * 512u + loff));
        bf16x8 r3 = *(const bf16x8*)((const char*)H + ((unsigned)s3 * 512u + loff));

        float e0 = v0 + stt; e0 = e0 > 0.f ? e0 : 0.2f * e0;
        float e1 = v1 + stt; e1 = e1 > 0.f ? e1 : 0.2f * e1;
        float e2 = v2 + stt; e2 = e2 > 0.f ? e2 : 0.2f * e2;
        float e3 = v3 + stt; e3 = e3 > 0.f ? e3 : 0.2f * e3;

        float w0 = __expf(e0);
        float w1 = (i0 + 1 < n) ? __expf(e1) : 0.f;
        float w2 = (i0 + 2 < n) ? __expf(e2) : 0.f;
        float w3 = (i0 + 3 < n) ? __expf(e3) : 0.f;

        denom += (w0 + w1) + (w2 + w3);
        #pragma unroll
        for (int e = 0; e < 8; ++e) {
            acc[e] += w0 * bf2f((bf16_t)r0[e]) + w1 * bf2f((bf16_t)r1[e])
                    + w2 * bf2f((bf16_t)r2[e]) + w3 * bf2f((bf16_t)r3[e]);
        }
    }

    const float inv = 1.f / (denom + 1e-8f);
    float r[8];
    #pragma unroll
    for (int e = 0; e < 8; ++e) r[e] = acc[e] * inv;

    if (residual) {
        bf16x8 xv = *(const bf16x8*)((const char*)X + (rowoff + loff));
        #pragma unroll
        for (int e = 0; e < 8; ++e) r[e] += bf2f((bf16_t)xv[e]);
    }

    bf16x8 o;
    #pragma unroll
    for (int e = 0; e < 8; ++e) {
        float x = r[e];
        x = x > 0.f ? x : (__expf(x) - 1.f);   // elu(alpha=1)
        o[e] = (short)f2bf(x);
    }
    *(bf16x8*)((char*)X + (rowoff + loff)) = o;
}

// ---------------- molecule mean pool (mol_ids int32, sorted) ----------------
__device__ inline int lower_bound_i(const int* a, int n, int v) {
    int lo = 0, hi = n;
    while (lo < hi) { int mid = (lo + hi) >> 1; if (a[mid] < v) lo = mid + 1; else hi = mid; }
    return lo;
}

__global__ __launch_bounds__(64) void pool_kernel(const bf16_t* __restrict__ X,
                                                  const int* __restrict__ mol,
                                                  float* __restrict__ out) {
    int m = blockIdx.x;
    int lane = threadIdx.x;
    int lo = lower_bound_i(mol, N_ATOMS, m);
    int hi = lower_bound_i(mol, N_ATOMS, m + 1);
    float ax = 0.f, ay = 0.f, az = 0.f, aw = 0.f;
    for (int i = lo; i < hi; ++i) {
        float4 v = ld4(&X[(long long)i * HID + lane * 4]);
        ax += v.x; ay += v.y; az += v.z; aw += v.w;
    }
    float c = (float)(hi - lo);
    float4 r = make_float4(0.f, 0.f, 0.f, 0.f);
    if (c > 0.f) {
        float inv = 1.f / c;
        r = make_float4(ax * inv, ay * inv, az * inv, aw * inv);
    }
    *(float4*)&out[(long long)m * HID + lane * 4] = r;
}

extern "C" void kernel_launch(void* const* d_in, const int* in_sizes, int n_in,
                              void* d_out, int out_size, void* d_ws, size_t ws_size,
                              hipStream_t stream) {
    const float* f_atoms = (const float*)d_in[0];
    const int*   ei      = (const int*)d_in[1];
    const int*   mol     = (const int*)d_in[2];
    const float* W0      = (const float*)d_in[3];
    const float* a0      = (const float*)d_in[4];
    const float* W1      = (const float*)d_in[5];
    const float* a1      = (const float*)d_in[6];
    const float* W2      = (const float*)d_in[7];
    const float* a2      = (const float*)d_in[8];
    float* out = (float*)d_out;

    char* ws = (char*)d_ws;
    size_t off = 0;
    bf16_t* X  = (bf16_t*)(ws + off); off += (size_t)N_ATOMS * HID * 2;   // 102.4 MB
    bf16_t* Hb = (bf16_t*)(ws + off); off += (size_t)N_ATOMS * HID * 2;   // 102.4 MB
    float* ss  = (float*)(ws + off);  off += (size_t)N_ATOMS * 4;
    float* st  = (float*)(ws + off);  off += (size_t)N_ATOMS * 4;
    int* cnt   = (int*)(ws + off);    off += (size_t)N_ATOMS * 4;
    int* lst   = (int*)(ws + off);    off += (size_t)N_ATOMS * CAP * 4;   // 25.6 MB
    if (ws_size < off) return;

    // d_out scratch: three transposed-weight buffers (344 KB total); pool
    // overwrites all of d_out at the end.
    char* ob = (char*)d_out;
    bf16_t* Wt0 = (bf16_t*)ob;                 // HID*160*2 = 81920 B
    bf16_t* Wt1 = (bf16_t*)(ob + 131072);      // HID*256*2 = 131072 B
    bf16_t* Wt2 = (bf16_t*)(ob + 262144);      // HID*256*2 = 131072 B

    hipMemsetAsync(cnt, 0, (size_t)N_ATOMS * 4, stream);
    build_adj<<<(N_EDGES + 255) / 256, 256, 0, stream>>>(ei, cnt, lst);

    // one fused transpose for all three layers (replaces 3 dispatches)
    const int t_elems = HID * 160 + 2 * HID * HID;   // 172032
    transpose_all<<<(t_elems + 255) / 256, 256, 0, stream>>>(W0, W1, W2, Wt0, Wt1, Wt2);

    const int gemm_blocks = (N_ATOMS + 127) / 128;   // 1563
    const int agg_blocks  = N_ATOMS / 8;             // 25000

    // ---- layer 0: A = f_atoms fp32, K=133 padded to 160 ----
    gemm_mfma<true, 5, FDIM, 160><<<gemm_blocks, 512, 0, stream>>>(f_atoms, Wt0, Hb, a0, ss, st);
    aggregate<<<agg_blocks, 256, 0, stream>>>(Hb, ss, st, cnt, lst, X, 0);

    // ---- layer 1 ----
    gemm_mfma<false, 8, HID, HID><<<gemm_blocks, 512, 0, stream>>>(X, Wt1, Hb, a1, ss, st);
    aggregate<<<agg_blocks, 256, 0, stream>>>(Hb, ss, st, cnt, lst, X, 1);

    // ---- layer 2 ----
    gemm_mfma<false, 8, HID, HID><<<gemm_blocks, 512, 0, stream>>>(X, Wt2, Hb, a2, ss, st);
    aggregate<<<agg_blocks, 256, 0, stream>>>(Hb, ss, st, cnt, lst, X, 1);

    pool_kernel<<<NMOLS, 64, 0, stream>>>(X, mol, out);
}